// Round 3
// baseline (311.052 us; speedup 1.0000x reference)
//
#include <hip/hip_runtime.h>
#include <hip/hip_bf16.h>
#include <cstdint>

// KAN MLP: 256->512->512->256, B=8192, cubic B-splines (uniform grid h=0.25,
// knots -1.75..1.75, 11 bases), BN at the end.
//
// Round-7: rounds 5/6 proved schedule changes alone don't move MfmaUtil off
// ~32% -- the binding ratio is staged-bytes/MFMA (192 B) and DS->MFMA
// serialization. This round:
//   - tile 256(M) x 256(N), BK=32 subtiles: staged 128 B/MFMA (1.5x less)
//   - 8 waves (2M x 4N), wave tile 128x64: acc[8][4], 12 ds_read_b128 and
//     32 MFMA per wave per subtile
//   - 4 LDS slots x 32 KB = 128 KB, staged 3 subtiles ahead, boundary
//     s_waitcnt vmcnt(8) (never drains the queue; 96 KB/CU in flight)
//   - counted lgkmcnt(7)/(4)/(0) + sched_barrier(0) between MFMA groups:
//     afr[1..7] reads drain UNDER the first MFMA groups (m201's actual
//     mechanism; round-5's lgkmcnt(0)-per-phase serialized instead)
//   - 2-bit row-XOR chunk swizzle (physical chunk = logical ^ (row&3)):
//     derivation gives max 2 lanes/bank on ds_read_b128 = free (m136)
//   - split-K partials in FP16 (unlocks SK=4 within the 33.5 MB budget;
//     2^-11 rel error is well under the bf16 A-staging error that
//     dominates absmax). C-writes also halve (WRITE_SIZE down).
// Grids: L0 (32,2,4), L1 (32,2,4), L2 (32,1,8) = 256 blocks = 1 block/CU.
//
// Workspace (146,800,640 bytes):
//   A   @ 0          : 8192*6144*2 = 100,663,296 (reused all layers)
//   W0  @ 100663296  : 3,145,728
//   W1  @ 103809024  : 6,291,456
//   W2  @ 110100480  : 3,145,728
//   P   @ 113246208  : fp16 partials, 33,554,432 (L0/L1: 4 x 8MB; L2: 8 x 4MB)

typedef unsigned short ushort_t;
typedef __bf16 bf16x8 __attribute__((ext_vector_type(8)));
typedef float f32x4 __attribute__((ext_vector_type(4)));
typedef _Float16 f16x2 __attribute__((ext_vector_type(2)));
typedef _Float16 f16x4 __attribute__((ext_vector_type(4)));

__device__ __forceinline__ ushort_t f2bf(float f) {
    __bf16 h = (__bf16)f;  // RNE
    return __builtin_bit_cast(ushort_t, h);
}

// async global->LDS 16B copy; LDS dest must be wave-uniform base + lane*16.
__device__ __forceinline__ void gload_lds16(const void* g, void* lds) {
    __builtin_amdgcn_global_load_lds(
        (const __attribute__((address_space(1))) unsigned int*)(uintptr_t)g,
        (__attribute__((address_space(3))) unsigned int*)(unsigned int)(uintptr_t)lds,
        16, 0, 0);
}

// x -> [gelu, b0..b10] (12 bf16). Direct cardinal cubic B-spline:
// basis_j(x) = b(xs - j), xs=(x+1.75)*4;  b(t), a=|t-2|:
//   a<=1: (4-6a^2+3a^3)/6 ; 1<a<2: (2-a)^3/6 ; else 0.
__device__ __forceinline__ void expand12(float x, ushort_t* o) {
    float x3 = x * x * x;
    float y  = 0.7978845608028654f * (x + 0.044715f * x3);
    float e  = __expf(2.0f * y);
    float th = 1.0f - 2.0f / (e + 1.0f);       // tanh(y)
    o[0] = f2bf(0.5f * x * (1.0f + th));
    float xs = (x + 1.75f) * 4.0f;
#pragma unroll
    for (int j = 0; j < 11; ++j) {
        float t  = xs - (float)j;
        float a  = fabsf(t - 2.0f);
        float p1 = (3.0f * a - 6.0f) * a * a + 4.0f;   // a<=1 branch
        float c  = 2.0f - a;
        float p2 = c * c * c;                          // 1<a<2 branch
        float v  = (a <= 1.0f) ? p1 : fmaxf(p2, 0.0f);
        o[1 + j] = f2bf(v * (1.0f / 6.0f));
    }
}

// ---------------------------------------------------------------------------
// Expansion from fp32 x (layer 0 only): 2 elements/thread.
// ---------------------------------------------------------------------------
__global__ __launch_bounds__(256) void expand_kernel(
    const float* __restrict__ X0, ushort_t* __restrict__ A, int total2)
{
    int idx = blockIdx.x * 256 + threadIdx.x;
    if (idx >= total2) return;
    float2 h = *(const float2*)(X0 + 2 * (size_t)idx);
    union { ushort_t us[24]; uint4 v[3]; } pk;
    expand12(h.x, pk.us);
    expand12(h.y, pk.us + 12);
    uint4* dst = (uint4*)(A + (size_t)idx * 24);
    dst[0] = pk.v[0]; dst[1] = pk.v[1]; dst[2] = pk.v[2];
}

// ---------------------------------------------------------------------------
// Expansion summing 4 fp16 split-K partials (previous layer's reduction).
// ---------------------------------------------------------------------------
__global__ __launch_bounds__(256) void expand_sum_kernel(
    const _Float16* __restrict__ P, size_t pstride,
    ushort_t* __restrict__ A, int total2)
{
    int idx = blockIdx.x * 256 + threadIdx.x;
    if (idx >= total2) return;
    float hx = 0.f, hy = 0.f;
#pragma unroll
    for (int s = 0; s < 4; ++s) {
        f16x2 v = *(const f16x2*)(P + s * pstride + 2 * (size_t)idx);
        hx += (float)v.x; hy += (float)v.y;
    }
    union { ushort_t us[24]; uint4 v[3]; } pk;
    expand12(hx, pk.us);
    expand12(hy, pk.us + 12);
    uint4* dst = (uint4*)(A + (size_t)idx * 24);
    dst[0] = pk.v[0]; dst[1] = pk.v[1]; dst[2] = pk.v[2];
}

// ---------------------------------------------------------------------------
// Weight pack (row-major): W[o][i*12+0]=base_w[o][i]; W[o][i*12+1+k]=spline_w.
// ---------------------------------------------------------------------------
__global__ __launch_bounds__(256) void pack_w_kernel(
    const float* __restrict__ bw, const float* __restrict__ sw,
    ushort_t* __restrict__ W, int total)
{
    int idx = blockIdx.x * 256 + threadIdx.x;
    if (idx >= total) return;
    union { ushort_t us[12]; uint2 v[3]; } pk;
    pk.us[0] = f2bf(bw[idx]);
    const float* s = sw + (size_t)idx * 11;
#pragma unroll
    for (int k = 0; k < 11; ++k) pk.us[1 + k] = f2bf(s[k]);
    uint2* dst = (uint2*)(W + (size_t)idx * 12);
    dst[0] = pk.v[0]; dst[1] = pk.v[1]; dst[2] = pk.v[2];
}

// ---------------------------------------------------------------------------
// GEMM: C_z[M,N] = A[M,kslice] @ W[N,kslice]^T (bf16 in, fp16 out).
// Tile 256x256, BK=32 subtiles, 512 threads = 8 waves (wm = w>>2, wn = w&3),
// wave tile 128x64 -> acc[8][4] of 16x16x32 MFMA (one per (mi,ni) per
// subtile). LDS: 4 slots of {A 256x32 (16KB) | B 256x32 (16KB)}; rows
// stored as 4 chunks of 16B, physical chunk = logical ^ (row&3).
//   A frag: lane holds A[m=l15][k=q*8+j];  C/D: D[m=q*4+r][n=l15].
// Pipeline: stage subtile t+3 at top of t (4 gloads/thread); boundary
// vmcnt(8) confirms t+1 resident with t+2/t+3 still in flight. Within the
// subtile, counted lgkmcnt(7)/(4)/(0) + sched_barrier(0) let afr[1..7]
// reads drain UNDER the first MFMA groups.
// Split-K over blockIdx.z -> C + z*M*N (fp16).
// ---------------------------------------------------------------------------
#define SLOTE 16384   // elements per LDS slot (32 KB): A 8192 + B 8192

__global__ __launch_bounds__(512, 2) void gemm_kernel(
    const ushort_t* __restrict__ A,  // M x K
    const ushort_t* __restrict__ W,  // N x K
    _Float16* __restrict__ C,        // split-K partials (fp16), z*M*N apart
    int M, int N, int K, int scps)   // scps = 32-chunks per split (>= 4)
{
    extern __shared__ __align__(16) ushort_t lds[];   // 4*SLOTE = 128 KB

    const int t   = threadIdx.x;
    const int l   = t & 63;
    const int w   = t >> 6;        // 0..7
    const int wm  = w >> 2;        // 0..1  (M half)
    const int wn  = w & 3;         // 0..3  (N quarter)
    const int l15 = l & 15;
    const int q   = l >> 4;        // 0..3
    const int blockM = blockIdx.x * 256;
    const int blockN = blockIdx.y * 256;
    const int kb0 = blockIdx.z * scps;
    const int nt  = scps;
    _Float16* Cz = C + (size_t)blockIdx.z * M * N;

    const ushort_t* Ab = A + (size_t)blockM * K;
    const ushort_t* Wb = W + (size_t)blockN * K;

    // stage one 32-k subtile: A 256 rows x 4 chunks (1024 chunk-slots) +
    // B same; 2+2 gloads/thread. s = (row<<2)|physchunk, logical = c^(row&3).
    auto stage = [&](int kb, int slot) {
        ushort_t* da = lds + slot * SLOTE;
        ushort_t* db = da + 8192;
#pragma unroll
        for (int it = 0; it < 2; ++it) {
            int s = it * 512 + t;
            int row = s >> 2, c = s & 3, g = c ^ (row & 3);
            gload_lds16(Ab + ((size_t)row * K + (kb << 5) + g * 8), da + s * 8);
        }
#pragma unroll
        for (int it = 0; it < 2; ++it) {
            int s = it * 512 + t;
            int row = s >> 2, c = s & 3, g = c ^ (row & 3);
            gload_lds16(Wb + ((size_t)row * K + (kb << 5) + g * 8), db + s * 8);
        }
    };

    f32x4 acc[8][4];
#pragma unroll
    for (int i = 0; i < 8; ++i)
#pragma unroll
        for (int j = 0; j < 4; ++j) acc[i][j] = (f32x4){0.f, 0.f, 0.f, 0.f};

    // prologue: stage subtiles 0,1,2 (nt >= 4 always)
    stage(kb0 + 0, 0); stage(kb0 + 1, 1); stage(kb0 + 2, 2);
    asm volatile("s_waitcnt vmcnt(8)" ::: "memory");   // subtile 0 resident
    __builtin_amdgcn_s_barrier();

    for (int tt = 0; tt < nt; ++tt) {
        const int slot = tt & 3;
        const ushort_t* Ac = lds + slot * SLOTE;
        const ushort_t* Bc = Ac + 8192;

        if (tt + 3 < nt) stage(kb0 + tt + 3, (tt + 3) & 3);

        // issue all 12 reads: B first (needed by every group), then A.
        bf16x8 bfr[4], afr[8];
#pragma unroll
        for (int ni = 0; ni < 4; ++ni) {
            int n = wn * 64 + ni * 16 + l15;
            bfr[ni] = *(const bf16x8*)&Bc[(size_t)((n << 2) + (q ^ (n & 3))) * 8];
        }
#pragma unroll
        for (int mi = 0; mi < 8; ++mi) {
            int m = wm * 128 + mi * 16 + l15;
            afr[mi] = *(const bf16x8*)&Ac[(size_t)((m << 2) + (q ^ (m & 3))) * 8];
        }

        // group 1: bfr0-3 + afr0 ready (7 newer reads outstanding)
        asm volatile("s_waitcnt lgkmcnt(7)" ::: "memory");
        __builtin_amdgcn_sched_barrier(0);
        __builtin_amdgcn_s_setprio(1);
#pragma unroll
        for (int ni = 0; ni < 4; ++ni)
            acc[0][ni] = __builtin_amdgcn_mfma_f32_16x16x32_bf16(
                afr[0], bfr[ni], acc[0][ni], 0, 0, 0);

        // group 2: afr1-3 ready (afr4-7 still draining under group-1 MFMAs)
        asm volatile("s_waitcnt lgkmcnt(4)" ::: "memory");
        __builtin_amdgcn_sched_barrier(0);
#pragma unroll
        for (int mi = 1; mi < 4; ++mi)
#pragma unroll
            for (int ni = 0; ni < 4; ++ni)
                acc[mi][ni] = __builtin_amdgcn_mfma_f32_16x16x32_bf16(
                    afr[mi], bfr[ni], acc[mi][ni], 0, 0, 0);

        // group 3: all reads done
        asm volatile("s_waitcnt lgkmcnt(0)" ::: "memory");
        __builtin_amdgcn_sched_barrier(0);
#pragma unroll
        for (int mi = 4; mi < 8; ++mi)
#pragma unroll
            for (int ni = 0; ni < 4; ++ni)
                acc[mi][ni] = __builtin_amdgcn_mfma_f32_16x16x32_bf16(
                    afr[mi], bfr[ni], acc[mi][ni], 0, 0, 0);
        __builtin_amdgcn_s_setprio(0);

        // boundary: confirm subtile t+1 resident; keep t+2/t+3 in flight.
        if (tt + 3 < nt)      asm volatile("s_waitcnt vmcnt(8)" ::: "memory");
        else if (tt + 2 < nt) asm volatile("s_waitcnt vmcnt(4)" ::: "memory");
        else if (tt + 1 < nt) asm volatile("s_waitcnt vmcnt(0)" ::: "memory");
        __builtin_amdgcn_s_barrier();
    }

    // epilogue: fp16 stores into this split's partial buffer
#pragma unroll
    for (int ni = 0; ni < 4; ++ni) {
        int n = blockN + wn * 64 + ni * 16 + l15;
#pragma unroll
        for (int mi = 0; mi < 8; ++mi) {
            int mb = blockM + wm * 128 + mi * 16 + q * 4;
#pragma unroll
            for (int r = 0; r < 4; ++r)
                Cz[(size_t)(mb + r) * N + n] = (_Float16)acc[mi][ni][r];
        }
    }
}

// ---------------------------------------------------------------------------
// Final: out = gamma*rsqrt(var+eps)*(sum of 8 fp16 partials - mean) + beta.
// ---------------------------------------------------------------------------
__global__ __launch_bounds__(256) void bn_reduce_kernel(
    const _Float16* __restrict__ Q, size_t qstride,
    const float* __restrict__ gamma, const float* __restrict__ beta,
    const float* __restrict__ mean,  const float* __restrict__ var,
    float4* __restrict__ out, int n4)
{
    int i = blockIdx.x * 256 + threadIdx.x;
    if (i >= n4) return;
    float sx = 0.f, sy = 0.f, sz = 0.f, sw = 0.f;
#pragma unroll
    for (int s = 0; s < 8; ++s) {
        f16x4 v = *(const f16x4*)(Q + s * qstride + 4 * (size_t)i);
        sx += (float)v.x; sy += (float)v.y; sz += (float)v.z; sw += (float)v.w;
    }
    int nb = (i * 4) & 255;
    float4 g  = *(const float4*)(gamma + nb);
    float4 be = *(const float4*)(beta + nb);
    float4 mn = *(const float4*)(mean + nb);
    float4 vr = *(const float4*)(var + nb);
    float4 o;
    o.x = g.x * rsqrtf(vr.x + 1e-5f) * (sx - mn.x) + be.x;
    o.y = g.y * rsqrtf(vr.y + 1e-5f) * (sy - mn.y) + be.y;
    o.z = g.z * rsqrtf(vr.z + 1e-5f) * (sz - mn.z) + be.z;
    o.w = g.w * rsqrtf(vr.w + 1e-5f) * (sw - mn.w) + be.w;
    out[i] = o;
}

// ---------------------------------------------------------------------------
extern "C" void kernel_launch(void* const* d_in, const int* in_sizes, int n_in,
                              void* d_out, int out_size, void* d_ws, size_t ws_size,
                              hipStream_t stream) {
    const float* x     = (const float*)d_in[0];
    const float* bw0   = (const float*)d_in[2];
    const float* sw0   = (const float*)d_in[3];
    const float* bw1   = (const float*)d_in[5];
    const float* sw1   = (const float*)d_in[6];
    const float* bw2   = (const float*)d_in[8];
    const float* sw2   = (const float*)d_in[9];
    const float* gamma = (const float*)d_in[10];
    const float* beta  = (const float*)d_in[11];
    const float* mean  = (const float*)d_in[12];
    const float* var   = (const float*)d_in[13];

    char* ws = (char*)d_ws;
    ushort_t*  Abuf = (ushort_t*)(ws);
    ushort_t*  W0   = (ushort_t*)(ws + 100663296);
    ushort_t*  W1   = (ushort_t*)(ws + 103809024);
    ushort_t*  W2   = (ushort_t*)(ws + 110100480);
    _Float16*  P    = (_Float16*)(ws + 113246208);   // 32 MB fp16 partials
    float*     out  = (float*)d_out;

    const size_t PS01 = (size_t)8192 * 512;   // L0/L1 partial stride (elems)
    const size_t PS2  = (size_t)8192 * 256;   // L2 partial stride (elems)
    const size_t GEMM_LDS = 4 * SLOTE * sizeof(ushort_t);  // 131072 B

    // weight packing (d_ws re-poisoned every call -> repack)
    pack_w_kernel<<<(512 * 256 + 255) / 256, 256, 0, stream>>>(bw0, sw0, W0, 512 * 256);
    pack_w_kernel<<<(512 * 512 + 255) / 256, 256, 0, stream>>>(bw1, sw1, W1, 512 * 512);
    pack_w_kernel<<<(256 * 512 + 255) / 256, 256, 0, stream>>>(bw2, sw2, W2, 256 * 512);

    // layer 0: K=3072 (96 x 32-chunks, 24/split), N=512, SK=4
    expand_kernel<<<4096, 256, 0, stream>>>(x, Abuf, 8192 * 256 / 2);
    {
        dim3 g(32, 2, 4);
        gemm_kernel<<<g, 512, GEMM_LDS, stream>>>(Abuf, W0, P, 8192, 512, 3072, 24);
    }
    // layer 1: K=6144 (192 x 32-chunks, 48/split), N=512, SK=4
    expand_sum_kernel<<<8192, 256, 0, stream>>>(P, PS01, Abuf, 8192 * 512 / 2);
    {
        dim3 g(32, 2, 4);
        gemm_kernel<<<g, 512, GEMM_LDS, stream>>>(Abuf, W1, P, 8192, 512, 6144, 48);
    }
    // layer 2: K=6144 (192 x 32-chunks, 24/split), N=256, SK=8
    expand_sum_kernel<<<8192, 256, 0, stream>>>(P, PS01, Abuf, 8192 * 512 / 2);
    {
        dim3 g(32, 1, 8);
        gemm_kernel<<<g, 512, GEMM_LDS, stream>>>(Abuf, W2, P, 8192, 256, 6144, 24);
    }
    // BN + 8-way split-K reduce -> out
    bn_reduce_kernel<<<2048, 256, 0, stream>>>(
        P, PS2, gamma, beta, mean, var, (float4*)out, 8192 * 256 / 4);
}